// Round 8
// baseline (157.099 us; speedup 1.0000x reference)
//
#include <hip/hip_runtime.h>

// KLD RepPoints loss, R7: fewer-but-wider gather instructions.
// Model fitting ALL of R0-R6: time ~ line-visits = sum(instrs x lines
// spanned). R2/R5/R6 (9x float2, stride 72): 776 visits/wave, all ~37us.
// R4 (9x float4, stride 144): 1424 -> 42us. R3 cut visits via LDS but
// paid more in barrier/LDS path. R7: same stride-72 mapping, but pred
// loaded as 5x dwordx4 from align16(e*72-8*(e&1)) + 18 cndmask selects
// (VALU is 90% idle), target as 2x dwordx4. 424 visits/wave = 1.83x less.
// No LDS, no atomics, two-kernel reduce.

__device__ __forceinline__ float kld_elem(
    const float px[9], const float py[9],
    const float tx[4], const float ty[4])
{
    // ---- pred moments ----
    const float inv9 = 1.0f / 9.0f;
    float sx = 0.f, sy = 0.f;
    #pragma unroll
    for (int k = 0; k < 9; ++k) { sx += px[k]; sy += py[k]; }
    float mux = sx * inv9, muy = sy * inv9;
    float a = 0.f, b = 0.f, d = 0.f;   // p_var = [[a,b],[b,d]]
    #pragma unroll
    for (int k = 0; k < 9; ++k) {
        float xx = px[k] - mux, yy = py[k] - muy;
        a += xx * xx; b += xx * yy; d += yy * yy;
    }
    a = a * inv9 + 1e-6f;
    b = b * inv9;
    d = d * inv9 + 1e-6f;

    // ---- target box -> rotated Gaussian ----
    float tmux = (tx[0] + tx[1] + tx[2] + tx[3]) * 0.25f;
    float tmuy = (ty[0] + ty[1] + ty[2] + ty[3]) * 0.25f;
    float e1x = tx[1] - tx[0], e1y = ty[1] - ty[0];
    float e2x = tx[2] - tx[1], e2y = ty[2] - ty[1];
    float w = e1x * e1x + e1y * e1y;
    float h = e2x * e2x + e2y * e2y;
    float sw = sqrtf(w);
    float c = e1x / sw, s = e1y / sw;
    const float invLL = 1.0f / 36.0f;      // 1/(4*L*L), L=3
    float dw = w * invLL, dh = h * invLL;
    float tv00 = c * c * dw + s * s * dh;  // t_var = R diag(dw,dh) R^T
    float tv01 = c * s * (dw - dh);
    float tv11 = s * s * dw + c * c * dh;

    float t_det = tv00 * tv11 - tv01 * tv01;
    float p_det = a * d - b * b;
    float inv_tdet = 1.0f / t_det;

    float dx = mux - tmux, dy = muy - tmuy;
    float term1 = (dx * dx * tv11 - 2.0f * dx * dy * tv01 + dy * dy * tv00) * inv_tdet;
    float trace = (tv11 * a - 2.0f * tv01 * b + tv00 * d) * inv_tdet;
    float term2 = trace + logf(t_det / p_det);
    float kld = 0.5f * (term1 + term2) - 1.0f;
    float kl = fmaxf(kld, 1e-6f);
    return 1.0f - 1.0f / (2.0f + sqrtf(kl));
}

__global__ __launch_bounds__(256) void kld_partial_kernel(
    const float* __restrict__ pred,    // [n][9][2]
    const float* __restrict__ target,  // [n][4][2]
    float* __restrict__ ws,            // [gridDim.x] partial sums
    int n_total)
{
    const int e = blockIdx.x * 256 + threadIdx.x;

    float loss = 0.0f;
    if (e < n_total) {
        const int odd = e & 1;
        float px[9], py[9], tx[4], ty[4];

        // last-even element: q[4] would overread 8B past pred end
        const bool tail_special = (e == n_total - 1) && !odd;
        if (!tail_special) {
            // aligned base: e*72 - 8*odd bytes = (e*18 - 2*odd) floats, 16B-aligned
            const float4* q =
                reinterpret_cast<const float4*>(pred + (size_t)e * 18 - 2 * odd);
            float4 q0 = q[0], q1 = q[1], q2 = q[2], q3 = q[3], q4 = q[4];
            float f[20] = {q0.x, q0.y, q0.z, q0.w,  q1.x, q1.y, q1.z, q1.w,
                           q2.x, q2.y, q2.z, q2.w,  q3.x, q3.y, q3.z, q3.w,
                           q4.x, q4.y, q4.z, q4.w};
            // float k of element at f[2*odd + k]
            #pragma unroll
            for (int j = 0; j < 9; ++j) {
                px[j] = odd ? f[2 * j + 2] : f[2 * j];
                py[j] = odd ? f[2 * j + 3] : f[2 * j + 1];
            }
        } else {
            // 1 thread at most: plain float2 path, no overread
            const float2* p = reinterpret_cast<const float2*>(pred) + (size_t)e * 9;
            #pragma unroll
            for (int j = 0; j < 9; ++j) { float2 v = p[j]; px[j] = v.x; py[j] = v.y; }
        }

        // target: 32B per element, always 16B-aligned
        const float4* t4 = reinterpret_cast<const float4*>(target) + (size_t)e * 2;
        float4 g0 = t4[0], g1 = t4[1];
        tx[0] = g0.x; ty[0] = g0.y;  tx[1] = g0.z; ty[1] = g0.w;
        tx[2] = g1.x; ty[2] = g1.y;  tx[3] = g1.z; ty[3] = g1.w;

        loss = kld_elem(px, py, tx, ty);
    }

    // ---- reduction: wave64 shuffle -> LDS -> one plain store per block ----
    #pragma unroll
    for (int off = 32; off > 0; off >>= 1)
        loss += __shfl_down(loss, off, 64);

    __shared__ float sm[4];
    int lane = threadIdx.x & 63;
    int wid  = threadIdx.x >> 6;
    if (lane == 0) sm[wid] = loss;
    __syncthreads();
    if (threadIdx.x == 0)
        ws[blockIdx.x] = sm[0] + sm[1] + sm[2] + sm[3];
}

__global__ __launch_bounds__(256) void kld_final_kernel(
    const float* __restrict__ ws, float* __restrict__ out,
    int nblocks, float inv_n)
{
    float s = 0.0f;
    for (int i = threadIdx.x; i < nblocks; i += 256)
        s += ws[i];

    #pragma unroll
    for (int off = 32; off > 0; off >>= 1)
        s += __shfl_down(s, off, 64);

    __shared__ float sm[4];
    int lane = threadIdx.x & 63;
    int wid  = threadIdx.x >> 6;
    if (lane == 0) sm[wid] = s;
    __syncthreads();
    if (threadIdx.x == 0)
        out[0] = (sm[0] + sm[1] + sm[2] + sm[3]) * inv_n;
}

extern "C" void kernel_launch(void* const* d_in, const int* in_sizes, int n_in,
                              void* d_out, int out_size, void* d_ws, size_t ws_size,
                              hipStream_t stream) {
    const float* pred   = (const float*)d_in[0];
    const float* target = (const float*)d_in[1];
    float* out = (float*)d_out;
    float* ws  = (float*)d_ws;

    int n = in_sizes[0] / 18;   // N elements (pred is N*9*2 floats)
    int nblocks = (n + 255) / 256;
    if (nblocks < 1) nblocks = 1;

    kld_partial_kernel<<<nblocks, 256, 0, stream>>>(pred, target, ws, n);
    kld_final_kernel<<<1, 256, 0, stream>>>(ws, out, nblocks, 1.0f / (float)n);
}

// Round 9
// 135.649 us; speedup vs baseline: 1.1581x; 1.1581x over previous
//
#include <hip/hip_runtime.h>

// KLD RepPoints loss, R8: wide-load gather, spill-proof (no arrays at all).
// R7 postmortem: WRITE_SIZE=82MB + VGPR=24 = the f[20] array spilled to
// scratch (SROA failed on variable-index GEP) -- R7 measured a scratch
// round-trip, not the wide-load idea. R8 is the same memory plan with 20
// named floats + 18 explicit ternaries (v_cndmask) and fully inlined scalar
// math. Line-visits/wave: 5x dwordx4 over stride-72 window + 2x dwordx4
// target = ~424 vs R2's 776 (9x float2 x 72 lines + 4 x 32).
// Two-kernel reduce, no LDS staging, no atomics.

__global__ __launch_bounds__(256) void kld_partial_kernel(
    const float* __restrict__ pred,    // [n][9][2]
    const float* __restrict__ target,  // [n][4][2]
    float* __restrict__ ws,            // [gridDim.x] partial sums
    int n_total)
{
    const int e = blockIdx.x * 256 + threadIdx.x;

    float loss = 0.0f;
    if (e < n_total) {
        const bool o = (e & 1) != 0;
        float px0, px1, px2, px3, px4, px5, px6, px7, px8;
        float py0, py1, py2, py3, py4, py5, py6, py7, py8;

        // last-even element would overread 8B past pred end via q[4]
        const bool tail_special = (e == n_total - 1) && !o;
        if (!tail_special) {
            // base = e*72 - 8*(e&1) bytes -> 16B-aligned
            const float4* q =
                reinterpret_cast<const float4*>(pred + (size_t)e * 18 - (o ? 2 : 0));
            float4 q0 = q[0], q1 = q[1], q2 = q[2], q3 = q[3], q4 = q[4];
            // even: pts at f[0..17]; odd: pts at f[2..19]  (f = flat 20 floats)
            px0 = o ? q0.z : q0.x;  py0 = o ? q0.w : q0.y;
            px1 = o ? q1.x : q0.z;  py1 = o ? q1.y : q0.w;
            px2 = o ? q1.z : q1.x;  py2 = o ? q1.w : q1.y;
            px3 = o ? q2.x : q1.z;  py3 = o ? q2.y : q1.w;
            px4 = o ? q2.z : q2.x;  py4 = o ? q2.w : q2.y;
            px5 = o ? q3.x : q2.z;  py5 = o ? q3.y : q2.w;
            px6 = o ? q3.z : q3.x;  py6 = o ? q3.w : q3.y;
            px7 = o ? q4.x : q3.z;  py7 = o ? q4.y : q3.w;
            px8 = o ? q4.z : q4.x;  py8 = o ? q4.w : q4.y;
        } else {
            // at most 1 thread in the grid: exact float2 loads, no overread
            const float2* p = reinterpret_cast<const float2*>(pred) + (size_t)e * 9;
            float2 v0 = p[0], v1 = p[1], v2 = p[2], v3 = p[3], v4 = p[4],
                   v5 = p[5], v6 = p[6], v7 = p[7], v8 = p[8];
            px0 = v0.x; py0 = v0.y;  px1 = v1.x; py1 = v1.y;
            px2 = v2.x; py2 = v2.y;  px3 = v3.x; py3 = v3.y;
            px4 = v4.x; py4 = v4.y;  px5 = v5.x; py5 = v5.y;
            px6 = v6.x; py6 = v6.y;  px7 = v7.x; py7 = v7.y;
            px8 = v8.x; py8 = v8.y;
        }

        // target: 32B per element, always 16B-aligned
        const float4* t4 = reinterpret_cast<const float4*>(target) + (size_t)e * 2;
        float4 g0 = t4[0], g1 = t4[1];
        float tx0 = g0.x, ty0 = g0.y, tx1 = g0.z, ty1 = g0.w;
        float tx2 = g1.x, ty2 = g1.y, tx3 = g1.z, ty3 = g1.w;

        // ---- pred moments (all scalar) ----
        const float inv9 = 1.0f / 9.0f;
        float sx = px0 + px1 + px2 + px3 + px4 + px5 + px6 + px7 + px8;
        float sy = py0 + py1 + py2 + py3 + py4 + py5 + py6 + py7 + py8;
        float mux = sx * inv9, muy = sy * inv9;

        float a, b, d;
        {
            float ux, uy;
            ux = px0 - mux; uy = py0 - muy; a  = ux * ux; b  = ux * uy; d  = uy * uy;
            ux = px1 - mux; uy = py1 - muy; a += ux * ux; b += ux * uy; d += uy * uy;
            ux = px2 - mux; uy = py2 - muy; a += ux * ux; b += ux * uy; d += uy * uy;
            ux = px3 - mux; uy = py3 - muy; a += ux * ux; b += ux * uy; d += uy * uy;
            ux = px4 - mux; uy = py4 - muy; a += ux * ux; b += ux * uy; d += uy * uy;
            ux = px5 - mux; uy = py5 - muy; a += ux * ux; b += ux * uy; d += uy * uy;
            ux = px6 - mux; uy = py6 - muy; a += ux * ux; b += ux * uy; d += uy * uy;
            ux = px7 - mux; uy = py7 - muy; a += ux * ux; b += ux * uy; d += uy * uy;
            ux = px8 - mux; uy = py8 - muy; a += ux * ux; b += ux * uy; d += uy * uy;
        }
        a = a * inv9 + 1e-6f;
        b = b * inv9;
        d = d * inv9 + 1e-6f;

        // ---- target box -> rotated Gaussian ----
        float tmux = (tx0 + tx1 + tx2 + tx3) * 0.25f;
        float tmuy = (ty0 + ty1 + ty2 + ty3) * 0.25f;
        float e1x = tx1 - tx0, e1y = ty1 - ty0;
        float e2x = tx2 - tx1, e2y = ty2 - ty1;
        float w = e1x * e1x + e1y * e1y;
        float h = e2x * e2x + e2y * e2y;
        float sw = sqrtf(w);
        float c = e1x / sw, s = e1y / sw;
        const float invLL = 1.0f / 36.0f;      // 1/(4*L*L), L=3
        float dw = w * invLL, dh = h * invLL;
        float tv00 = c * c * dw + s * s * dh;  // t_var = R diag(dw,dh) R^T
        float tv01 = c * s * (dw - dh);
        float tv11 = s * s * dw + c * c * dh;

        float t_det = tv00 * tv11 - tv01 * tv01;
        float p_det = a * d - b * b;
        float inv_tdet = 1.0f / t_det;

        float dx = mux - tmux, dy = muy - tmuy;
        float term1 = (dx * dx * tv11 - 2.0f * dx * dy * tv01 + dy * dy * tv00) * inv_tdet;
        float trace = (tv11 * a - 2.0f * tv01 * b + tv00 * d) * inv_tdet;
        float term2 = trace + logf(t_det / p_det);
        float kld = 0.5f * (term1 + term2) - 1.0f;
        float kl = fmaxf(kld, 1e-6f);
        loss = 1.0f - 1.0f / (2.0f + sqrtf(kl));
    }

    // ---- reduction: wave64 shuffle -> LDS -> one plain store per block ----
    #pragma unroll
    for (int off = 32; off > 0; off >>= 1)
        loss += __shfl_down(loss, off, 64);

    __shared__ float sm[4];
    int lane = threadIdx.x & 63;
    int wid  = threadIdx.x >> 6;
    if (lane == 0) sm[wid] = loss;
    __syncthreads();
    if (threadIdx.x == 0)
        ws[blockIdx.x] = sm[0] + sm[1] + sm[2] + sm[3];
}

__global__ __launch_bounds__(256) void kld_final_kernel(
    const float* __restrict__ ws, float* __restrict__ out,
    int nblocks, float inv_n)
{
    float s = 0.0f;
    for (int i = threadIdx.x; i < nblocks; i += 256)
        s += ws[i];

    #pragma unroll
    for (int off = 32; off > 0; off >>= 1)
        s += __shfl_down(s, off, 64);

    __shared__ float sm[4];
    int lane = threadIdx.x & 63;
    int wid  = threadIdx.x >> 6;
    if (lane == 0) sm[wid] = s;
    __syncthreads();
    if (threadIdx.x == 0)
        out[0] = (sm[0] + sm[1] + sm[2] + sm[3]) * inv_n;
}

extern "C" void kernel_launch(void* const* d_in, const int* in_sizes, int n_in,
                              void* d_out, int out_size, void* d_ws, size_t ws_size,
                              hipStream_t stream) {
    const float* pred   = (const float*)d_in[0];
    const float* target = (const float*)d_in[1];
    float* out = (float*)d_out;
    float* ws  = (float*)d_ws;

    int n = in_sizes[0] / 18;   // N elements (pred is N*9*2 floats)
    int nblocks = (n + 255) / 256;
    if (nblocks < 1) nblocks = 1;

    kld_partial_kernel<<<nblocks, 256, 0, stream>>>(pred, target, ws, n);
    kld_final_kernel<<<1, 256, 0, stream>>>(ws, out, nblocks, 1.0f / (float)n);
}

// Round 10
// 135.402 us; speedup vs baseline: 1.1602x; 1.0018x over previous
//
#include <hip/hip_runtime.h>

// KLD RepPoints loss, R9: R6's 2-deep pipeline + sched_barrier(0) to PIN it.
// Key realization (R2..R8 all flat at ~37us / 2.8 TB/s): VGPR_Count=24 on
// kernels keeping 26-52 loaded floats "live" proves LLVM re-schedules every
// source variant into load->use->load->use chains (~7 lines in flight/wave)
// to minimize registers. Source-level MLP never reached the ISA. Fix:
// __builtin_amdgcn_sched_barrier(0) after the 26-load block -- loads can't
// sink past it, compute can't hoist above it -> all ~28 lines/wave truly
// outstanding. Expect VGPR ~60-80, BW 2.8 -> ~5+ TB/s if the model is right.

__device__ __forceinline__ float kld_elem(
    float px0, float px1, float px2, float px3, float px4,
    float px5, float px6, float px7, float px8,
    float py0, float py1, float py2, float py3, float py4,
    float py5, float py6, float py7, float py8,
    float tx0, float ty0, float tx1, float ty1,
    float tx2, float ty2, float tx3, float ty3)
{
    // ---- pred moments ----
    const float inv9 = 1.0f / 9.0f;
    float sx = px0 + px1 + px2 + px3 + px4 + px5 + px6 + px7 + px8;
    float sy = py0 + py1 + py2 + py3 + py4 + py5 + py6 + py7 + py8;
    float mux = sx * inv9, muy = sy * inv9;

    float a, b, d, ux, uy;
    ux = px0 - mux; uy = py0 - muy; a  = ux * ux; b  = ux * uy; d  = uy * uy;
    ux = px1 - mux; uy = py1 - muy; a += ux * ux; b += ux * uy; d += uy * uy;
    ux = px2 - mux; uy = py2 - muy; a += ux * ux; b += ux * uy; d += uy * uy;
    ux = px3 - mux; uy = py3 - muy; a += ux * ux; b += ux * uy; d += uy * uy;
    ux = px4 - mux; uy = py4 - muy; a += ux * ux; b += ux * uy; d += uy * uy;
    ux = px5 - mux; uy = py5 - muy; a += ux * ux; b += ux * uy; d += uy * uy;
    ux = px6 - mux; uy = py6 - muy; a += ux * ux; b += ux * uy; d += uy * uy;
    ux = px7 - mux; uy = py7 - muy; a += ux * ux; b += ux * uy; d += uy * uy;
    ux = px8 - mux; uy = py8 - muy; a += ux * ux; b += ux * uy; d += uy * uy;
    a = a * inv9 + 1e-6f;
    b = b * inv9;
    d = d * inv9 + 1e-6f;

    // ---- target box -> rotated Gaussian ----
    float tmux = (tx0 + tx1 + tx2 + tx3) * 0.25f;
    float tmuy = (ty0 + ty1 + ty2 + ty3) * 0.25f;
    float e1x = tx1 - tx0, e1y = ty1 - ty0;
    float e2x = tx2 - tx1, e2y = ty2 - ty1;
    float w = e1x * e1x + e1y * e1y;
    float h = e2x * e2x + e2y * e2y;
    float sw = sqrtf(w);
    float c = e1x / sw, s = e1y / sw;
    const float invLL = 1.0f / 36.0f;      // 1/(4*L*L), L=3
    float dw = w * invLL, dh = h * invLL;
    float tv00 = c * c * dw + s * s * dh;  // t_var = R diag(dw,dh) R^T
    float tv01 = c * s * (dw - dh);
    float tv11 = s * s * dw + c * c * dh;

    float t_det = tv00 * tv11 - tv01 * tv01;
    float p_det = a * d - b * b;
    float inv_tdet = 1.0f / t_det;

    float dx = mux - tmux, dy = muy - tmuy;
    float term1 = (dx * dx * tv11 - 2.0f * dx * dy * tv01 + dy * dy * tv00) * inv_tdet;
    float trace = (tv11 * a - 2.0f * tv01 * b + tv00 * d) * inv_tdet;
    float term2 = trace + logf(t_det / p_det);
    float kld = 0.5f * (term1 + term2) - 1.0f;
    float kl = fmaxf(kld, 1e-6f);
    return 1.0f - 1.0f / (2.0f + sqrtf(kl));
}

__global__ __launch_bounds__(256) void kld_partial_kernel(
    const float* __restrict__ pred,    // [n][9][2]
    const float* __restrict__ target,  // [n][4][2]
    float* __restrict__ ws,            // [gridDim.x] partial sums
    int n_total)
{
    const int tid0   = blockIdx.x * 256 + threadIdx.x;
    const int stride = gridDim.x * 256;
    const int nm1    = n_total - 1;

    // element indices, clamped (loads always in-bounds; invalid -> weight 0)
    int eA = tid0;            bool vA = (eA <= nm1); eA = vA ? eA : nm1;
    int eB = tid0 + stride;   bool vB = (eB <= nm1); eB = vB ? eB : nm1;

    const float2* pA = reinterpret_cast<const float2*>(pred)   + (size_t)eA * 9;
    const float2* tA = reinterpret_cast<const float2*>(target) + (size_t)eA * 4;
    const float2* pB = reinterpret_cast<const float2*>(pred)   + (size_t)eB * 9;
    const float2* tB = reinterpret_cast<const float2*>(target) + (size_t)eB * 4;

    // ---- issue ALL 26 loads; sched_barrier pins them ABOVE all compute ----
    float2 a0 = pA[0], a1 = pA[1], a2 = pA[2], a3 = pA[3], a4 = pA[4],
           a5 = pA[5], a6 = pA[6], a7 = pA[7], a8 = pA[8];
    float2 qa0 = tA[0], qa1 = tA[1], qa2 = tA[2], qa3 = tA[3];
    float2 b0 = pB[0], b1 = pB[1], b2 = pB[2], b3 = pB[3], b4 = pB[4],
           b5 = pB[5], b6 = pB[6], b7 = pB[7], b8 = pB[8];
    float2 qb0 = tB[0], qb1 = tB[1], qb2 = tB[2], qb3 = tB[3];

    __builtin_amdgcn_sched_barrier(0);   // no instruction crosses this point

    float lossA = kld_elem(a0.x, a1.x, a2.x, a3.x, a4.x, a5.x, a6.x, a7.x, a8.x,
                           a0.y, a1.y, a2.y, a3.y, a4.y, a5.y, a6.y, a7.y, a8.y,
                           qa0.x, qa0.y, qa1.x, qa1.y, qa2.x, qa2.y, qa3.x, qa3.y);
    float lossB = kld_elem(b0.x, b1.x, b2.x, b3.x, b4.x, b5.x, b6.x, b7.x, b8.x,
                           b0.y, b1.y, b2.y, b3.y, b4.y, b5.y, b6.y, b7.y, b8.y,
                           qb0.x, qb0.y, qb1.x, qb1.y, qb2.x, qb2.y, qb3.x, qb3.y);

    float loss = (vA ? lossA : 0.0f) + (vB ? lossB : 0.0f);

    // ---- reduction: wave64 shuffle -> LDS -> one plain store per block ----
    #pragma unroll
    for (int off = 32; off > 0; off >>= 1)
        loss += __shfl_down(loss, off, 64);

    __shared__ float sm[4];
    int lane = threadIdx.x & 63;
    int wid  = threadIdx.x >> 6;
    if (lane == 0) sm[wid] = loss;
    __syncthreads();
    if (threadIdx.x == 0)
        ws[blockIdx.x] = sm[0] + sm[1] + sm[2] + sm[3];
}

__global__ __launch_bounds__(256) void kld_final_kernel(
    const float* __restrict__ ws, float* __restrict__ out,
    int nblocks, float inv_n)
{
    float s = 0.0f;
    for (int i = threadIdx.x; i < nblocks; i += 256)
        s += ws[i];

    #pragma unroll
    for (int off = 32; off > 0; off >>= 1)
        s += __shfl_down(s, off, 64);

    __shared__ float sm[4];
    int lane = threadIdx.x & 63;
    int wid  = threadIdx.x >> 6;
    if (lane == 0) sm[wid] = s;
    __syncthreads();
    if (threadIdx.x == 0)
        out[0] = (sm[0] + sm[1] + sm[2] + sm[3]) * inv_n;
}

extern "C" void kernel_launch(void* const* d_in, const int* in_sizes, int n_in,
                              void* d_out, int out_size, void* d_ws, size_t ws_size,
                              hipStream_t stream) {
    const float* pred   = (const float*)d_in[0];
    const float* target = (const float*)d_in[1];
    float* out = (float*)d_out;
    float* ws  = (float*)d_ws;

    int n = in_sizes[0] / 18;           // N elements (pred is N*9*2 floats)
    int nblocks = (n + 511) / 512;      // 2 elements per thread
    if (nblocks < 1) nblocks = 1;

    kld_partial_kernel<<<nblocks, 256, 0, stream>>>(pred, target, ws, n);
    kld_final_kernel<<<1, 256, 0, stream>>>(ws, out, nblocks, 1.0f / (float)n);
}